// Round 3
// baseline (111.806 us; speedup 1.0000x reference)
//
#include <hip/hip_runtime.h>
#include <hip/hip_bf16.h>

// RNN_73048803770905: fused [B,T,200]x[200,64] projection + 128-step tanh RNN + sigmoid head.
// B=4096, T=128, D_IN=200, H=64. HBM floor ~67us (419 MB x read).
// R3: independent waves (4 batch rows each), per-wave ILP attack on the serial chain:
//  - recurrence split into 2 independent sub-chains (rows 01 / 23), interleaved
//  - projection software-pipelined one chunk ahead (xps double buffer) so its
//    MFMAs fill the chain's stall slots
//  - xps stores {lo,hi,lo,hi} per chain: step C-init = 1 ds_read_b128 per n-tile

#define TSEQ 128
#define DIN  200
#define HID  64
#define TC   4
#define NCH  (TSEQ/TC)

typedef short bf16x8 __attribute__((ext_vector_type(8)));
typedef float f32x4  __attribute__((ext_vector_type(4)));

__device__ __forceinline__ short f2bf(float f) {
  __hip_bfloat16 h = __float2bfloat16(f);
  return __builtin_bit_cast(short, h);
}
__device__ __forceinline__ bf16x8 cvt8(f32x4 a, f32x4 b) {
  bf16x8 r;
#pragma unroll
  for (int i = 0; i < 4; ++i) { r[i] = f2bf(a[i]); r[4 + i] = f2bf(b[i]); }
  return r;
}
// tanh(x) = 1 - 2/(1 + 2^(x*2/ln2)); v_exp_f32 handles inf/0.
__device__ __forceinline__ float tanh_fast(float x) {
  float e = exp2f(x * 2.885390081777927f);
  float r = __builtin_amdgcn_rcpf(1.f + e);
  return __builtin_fmaf(-2.f, r, 1.f);
}

__global__ __launch_bounds__(256, 1) void rnn_fused(
    const float* __restrict__ x,   const float* __restrict__ Wih,
    const float* __restrict__ Whh, const float* __restrict__ bih,
    const float* __restrict__ bhh, const float* __restrict__ Wout,
    const float* __restrict__ bout, float* __restrict__ out)
{
  // [buf][wave][chain][tl][col][slot]  slots = {lo,hi,lo,hi} batch rows of the chain
  __shared__ float          xps[2][4][2][TC][HID][4];   // 64 KB
  __shared__ unsigned short hb [4][2][2][HID];          // [wave][chain][row01][col], 2 KB

  const int tid  = threadIdx.x;
  const int w    = tid >> 6;
  const int lane = tid & 63;
  const int m    = lane & 15;
  const int g    = lane >> 4;
  const int bw   = blockIdx.x * 16 + w * 4;   // wave's first batch row

  // projection A-tile row = rb*4 + tl  (rb = m>>2 batch row, tl = m&3 timestep)
  const float* xrow = x + ((size_t)(bw + (m >> 2)) * TSEQ + (m & 3)) * DIN;

  f32x4 pA[7][2], pB[7][2];
  auto LOADC = [&](f32x4 (&P)[7][2], int c) {
#pragma unroll
    for (int ks = 0; ks < 7; ++ks) {
      const int d = ks * 32 + g * 8;
      const float* p = xrow + (size_t)c * (TC * DIN);
      if (d + 8 <= DIN) {
        P[ks][0] = *reinterpret_cast<const f32x4*>(p + d);
        P[ks][1] = *reinterpret_cast<const f32x4*>(p + d + 4);
      } else {
        P[ks][0] = (f32x4)0.f; P[ks][1] = (f32x4)0.f;   // d>=200 tail stays zero
      }
    }
  };
  LOADC(pA, 0); LOADC(pB, 1);

  // ---- weights into registers ----
  bf16x8 wihf[4][7];   // B[k=d][n=h]: lane h = nt*16+m, d = ks*32+g*8+j
#pragma unroll
  for (int nt = 0; nt < 4; ++nt) {
    const float* wr = Wih + (size_t)(nt * 16 + m) * DIN;
#pragma unroll
    for (int ks = 0; ks < 7; ++ks) {
      const int d = ks * 32 + g * 8;
      if (d + 8 <= DIN)
        wihf[nt][ks] = cvt8(*reinterpret_cast<const f32x4*>(wr + d),
                            *reinterpret_cast<const f32x4*>(wr + d + 4));
      else
        wihf[nt][ks] = (bf16x8)0;
    }
  }
  bf16x8 whhf[4][2];   // B[k][n=h]: lane h = nt*16+m, k = hf*32+g*8+j
#pragma unroll
  for (int nt = 0; nt < 4; ++nt)
#pragma unroll
    for (int hf = 0; hf < 2; ++hf) {
      const float* wr = Whh + (size_t)(nt * 16 + m) * HID + hf * 32 + g * 8;
      whhf[nt][hf] = cvt8(*reinterpret_cast<const f32x4*>(wr),
                          *reinterpret_cast<const f32x4*>(wr + 4));
    }
  float biasv[4];
#pragma unroll
  for (int nt = 0; nt < 4; ++nt) biasv[nt] = bih[nt * 16 + m] + bhh[nt * 16 + m];
  const float woutv = Wout[g * 16 + m];
  const float bout0 = bout[0];

  // zero own wave's h state (h_{-1} = 0): 128 dwords per wave
  reinterpret_cast<unsigned int*>(&hb[w][0][0][0])[lane]      = 0u;
  reinterpret_cast<unsigned int*>(&hb[w][0][0][0])[lane + 64] = 0u;

  // projection for one chunk -> xq[chain][tl][col][slot]
  auto PROJ = [&](f32x4 (&P)[7][2], float (*xq)[TC][HID][4]) {
    bf16x8 afr[7];
#pragma unroll
    for (int ks = 0; ks < 7; ++ks) afr[ks] = cvt8(P[ks][0], P[ks][1]);
    f32x4 acc[4];
#pragma unroll
    for (int nt = 0; nt < 4; ++nt) acc[nt] = (f32x4)(biasv[nt]);
#pragma unroll
    for (int ks = 0; ks < 7; ++ks)
#pragma unroll
      for (int nt = 0; nt < 4; ++nt)
        acc[nt] = __builtin_amdgcn_mfma_f32_16x16x32_bf16(afr[ks], wihf[nt][ks], acc[nt], 0, 0, 0);
    // lane (g,m) holds xp[t=rr][batch g][col nt*16+m]; dup into slots (g&1), (g&1)+2
#pragma unroll
    for (int nt = 0; nt < 4; ++nt)
#pragma unroll
      for (int rr = 0; rr < 4; ++rr) {
        float v = acc[nt][rr];
        float* bp = &xq[g >> 1][rr][nt * 16 + m][0];
        bp[g & 1] = v; bp[(g & 1) + 2] = v;
      }
  };

  float vf0 = 0.f, vf1 = 0.f, vf2 = 0.f, vf3 = 0.f;

  // 4 recurrence steps of one chunk; two independent sub-chains interleaved
  auto STEPS = [&](float (*xq)[TC][HID][4]) {
#pragma unroll
    for (int tl = 0; tl < TC; ++tl) {
      f32x4 ra[4], rb[4];
#pragma unroll
      for (int nt = 0; nt < 4; ++nt) {
        ra[nt] = *reinterpret_cast<const f32x4*>(&xq[0][tl][nt * 16 + m][0]);
        rb[nt] = *reinterpret_cast<const f32x4*>(&xq[1][tl][nt * 16 + m][0]);
      }
      // A-frags: row m -> h[chain][m&1], cols g*8+j (k<32) and 32+g*8+j (k>=32)
      bf16x8 aA0 = *reinterpret_cast<const bf16x8*>(&hb[w][0][m & 1][g * 8]);
      bf16x8 aA1 = *reinterpret_cast<const bf16x8*>(&hb[w][0][m & 1][32 + g * 8]);
      bf16x8 aB0 = *reinterpret_cast<const bf16x8*>(&hb[w][1][m & 1][g * 8]);
      bf16x8 aB1 = *reinterpret_cast<const bf16x8*>(&hb[w][1][m & 1][32 + g * 8]);
#pragma unroll
      for (int nt = 0; nt < 4; ++nt) {
        ra[nt] = __builtin_amdgcn_mfma_f32_16x16x32_bf16(aA0, whhf[nt][0], ra[nt], 0, 0, 0);
        rb[nt] = __builtin_amdgcn_mfma_f32_16x16x32_bf16(aB0, whhf[nt][0], rb[nt], 0, 0, 0);
      }
#pragma unroll
      for (int nt = 0; nt < 4; ++nt) {
        ra[nt] = __builtin_amdgcn_mfma_f32_16x16x32_bf16(aA1, whhf[nt][1], ra[nt], 0, 0, 0);
        rb[nt] = __builtin_amdgcn_mfma_f32_16x16x32_bf16(aB1, whhf[nt][1], rb[nt], 0, 0, 0);
      }
      // D row 4g+r -> batch (r&1); each g-group owns n-tile nt=g
      float aLo = (g == 0) ? ra[0][0] : (g == 1) ? ra[1][0] : (g == 2) ? ra[2][0] : ra[3][0];
      float aHi = (g == 0) ? ra[0][1] : (g == 1) ? ra[1][1] : (g == 2) ? ra[2][1] : ra[3][1];
      float bLo = (g == 0) ? rb[0][0] : (g == 1) ? rb[1][0] : (g == 2) ? rb[2][0] : rb[3][0];
      float bHi = (g == 0) ? rb[0][1] : (g == 1) ? rb[1][1] : (g == 2) ? rb[2][1] : rb[3][1];
      aLo = tanh_fast(aLo); aHi = tanh_fast(aHi);
      bLo = tanh_fast(bLo); bHi = tanh_fast(bHi);
      const int col = g * 16 + m;
      hb[w][0][0][col] = (unsigned short)f2bf(aLo);
      hb[w][0][1][col] = (unsigned short)f2bf(aHi);
      hb[w][1][0][col] = (unsigned short)f2bf(bLo);
      hb[w][1][1][col] = (unsigned short)f2bf(bHi);
      vf0 = aLo; vf1 = aHi; vf2 = bLo; vf3 = bHi;   // final step's values survive
    }
  };

  // ---- prologue: xp(0) into buf0; refill pA with chunk 2 ----
  PROJ(pA, &xps[0][w][0]);
  LOADC(pA, 2);

  // ---- main: body(c) = { proj(c+1) -> other buf, steps(c) } ----
  for (int c = 0; c < NCH; c += 2) {
    PROJ(pB, &xps[1][w][0]);                    // chunk c+1 (c <= 30 so always valid)
    if (c + 3 < NCH) LOADC(pB, c + 3);
    STEPS(&xps[0][w][0]);                       // chunk c
    if (c + 2 < NCH) PROJ(pA, &xps[0][w][0]);   // chunk c+2
    if (c + 4 < NCH) LOADC(pA, c + 4);
    STEPS(&xps[1][w][0]);                       // chunk c+1
  }

  // ---- epilogue: out[bw+r] = sigmoid(h_last[r] . Wout + bout) ----
  f32x4 s; s[0] = vf0 * woutv; s[1] = vf1 * woutv; s[2] = vf2 * woutv; s[3] = vf3 * woutv;
#pragma unroll
  for (int mask = 1; mask < 64; mask <<= 1) {
#pragma unroll
    for (int r = 0; r < 4; ++r) s[r] += __shfl_xor(s[r], mask, 64);
  }
  if (lane == 0) {
    f32x4 o;
#pragma unroll
    for (int r = 0; r < 4; ++r) {
      const float z = s[r] + bout0;
      o[r] = __builtin_amdgcn_rcpf(1.f + exp2f(-z * 1.4426950408889634f));
    }
    *reinterpret_cast<f32x4*>(out + bw) = o;
  }
}

extern "C" void kernel_launch(void* const* d_in, const int* in_sizes, int n_in,
                              void* d_out, int out_size, void* d_ws, size_t ws_size,
                              hipStream_t stream) {
  const float* x    = (const float*)d_in[0];
  const float* Wih  = (const float*)d_in[1];
  const float* Whh  = (const float*)d_in[2];
  const float* bih  = (const float*)d_in[3];
  const float* bhh  = (const float*)d_in[4];
  const float* Wout = (const float*)d_in[5];
  const float* bout = (const float*)d_in[6];
  float* out = (float*)d_out;

  const int B = in_sizes[0] / (TSEQ * DIN);   // 4096
  rnn_fused<<<dim3(B / 16), dim3(256), 0, stream>>>(x, Wih, Whh, bih, bhh, Wout, bout, out);
}

// Round 4
// 107.249 us; speedup vs baseline: 1.0425x; 1.0425x over previous
//
#include <hip/hip_runtime.h>
#include <hip/hip_bf16.h>

// RNN_73048803770905: fused [B,T,200]x[200,64] projection + 128-step tanh RNN + sigmoid head.
// B=4096, T=128, D_IN=200, H=64. HBM floor ~67us (419 MB x read once).
// R4: R1-R3 all hit ~4.2 TB/s with MFMA-frag-layout (800B-strided) global loads ->
// pattern-limited. Fix: CONTIGUOUS per-wave streaming loads (lane L <- chunk byte L*16),
// bf16 cvt, LDS transpose stage (write linear, read in frag layout). Wih frags in shared
// LDS (-112 VGPR) -> 2 blocks/CU (2 waves/SIMD). Wave owns 2 rows; chunk = 8 timesteps;
// zero in-loop barriers (all LDS regions per-wave; wihL read-only after one init barrier).

#define TSEQ 128
#define DIN  200
#define HID  64
#define CT   8
#define NCH  (TSEQ/CT)
#define STG_T 208            // u16 stride per (row,t) in stage: 416B, 16B-aligned, bank-spread

typedef short bf16x8 __attribute__((ext_vector_type(8)));
typedef float f32x4  __attribute__((ext_vector_type(4)));
typedef float f32x2  __attribute__((ext_vector_type(2)));
typedef unsigned int u32x2 __attribute__((ext_vector_type(2)));

__device__ __forceinline__ unsigned short f2bf(float f) {
  __hip_bfloat16 h = __float2bfloat16(f);
  return __builtin_bit_cast(unsigned short, h);
}
__device__ __forceinline__ bf16x8 cvt8(f32x4 a, f32x4 b) {
  bf16x8 r;
#pragma unroll
  for (int i = 0; i < 4; ++i) {
    r[i]     = (short)f2bf(a[i]);
    r[4 + i] = (short)f2bf(b[i]);
  }
  return r;
}
// tanh(x) = 1 - 2/(1 + 2^(x*2/ln2)); v_exp_f32 handles the extremes.
__device__ __forceinline__ float tanh_fast(float x) {
  float e = exp2f(x * 2.885390081777927f);
  float r = __builtin_amdgcn_rcpf(1.f + e);
  return __builtin_fmaf(-2.f, r, 1.f);
}

__global__ __launch_bounds__(256, 2) void rnn_fused(
    const float* __restrict__ x,   const float* __restrict__ Wih,
    const float* __restrict__ Whh, const float* __restrict__ bih,
    const float* __restrict__ bhh, const float* __restrict__ Wout,
    const float* __restrict__ bout, float* __restrict__ out)
{
  __shared__ unsigned short wihL[28][64][8];       // Wih bf16 frags, shared: 28 KB
  __shared__ unsigned short stg[4][2][CT * STG_T]; // per-wave x stage (bf16): 26 KB
  __shared__ float          xpl[4][CT][HID][2];    // per-wave xp [t][h][batch]: 16 KB
  __shared__ unsigned short hbl[4][2][72];         // per-wave h state [batch][col]: 1.1 KB

  const int tid  = threadIdx.x;
  const int w    = tid >> 6;
  const int lane = tid & 63;
  const int m    = lane & 15;
  const int g    = lane >> 4;
  const int r0   = blockIdx.x * 8 + w * 2;         // wave's first batch row (512 blocks)

  // ---- contiguous streaming loads: lane L covers bytes [i*1024 + L*16) of the
  // wave's dense (row, 8-timestep) 6.4KB block. 6 full instrs + 1 quarter (16 lanes).
  f32x4 pld[2][7];
  auto LOADC = [&](int c) {
#pragma unroll
    for (int r = 0; r < 2; ++r) {
      const float* bp = x + (size_t)(r0 + r) * (TSEQ * DIN) + (size_t)c * (CT * DIN);
#pragma unroll
      for (int i = 0; i < 7; ++i) {
        if (i < 6)          pld[r][i] = *reinterpret_cast<const f32x4*>(bp + i * 256 + lane * 4);
        else if (lane < 16) pld[r][6] = *reinterpret_cast<const f32x4*>(bp + 1536 + lane * 4);
      }
    }
  };
  LOADC(0);   // chunk 0 in flight during init

  // ---- fill shared Wih frags: frag f=nt*7+ks, lane (m,g) holds Wih[nt*16+m][ks*32+g*8 ..+7]
  for (int f = w; f < 28; f += 4) {
    const int nt = f / 7, ks = f % 7;
    const int d  = ks * 32 + g * 8;
    bf16x8 v = (bf16x8)0;
    if (d + 8 <= DIN) {
      const float* wr = Wih + (size_t)(nt * 16 + m) * DIN + d;
      v = cvt8(*reinterpret_cast<const f32x4*>(wr), *reinterpret_cast<const f32x4*>(wr + 4));
    }
    *reinterpret_cast<bf16x8*>(&wihL[f][lane][0]) = v;
  }

  // ---- Whh frags in regs (32 VGPR): B[k][n=h], lane h = nt*16+m, k = hf*32+g*8+j
  bf16x8 whhf[4][2];
#pragma unroll
  for (int nt = 0; nt < 4; ++nt)
#pragma unroll
    for (int hf = 0; hf < 2; ++hf) {
      const float* wr = Whh + (size_t)(nt * 16 + m) * HID + hf * 32 + g * 8;
      whhf[nt][hf] = cvt8(*reinterpret_cast<const f32x4*>(wr),
                          *reinterpret_cast<const f32x4*>(wr + 4));
    }
  float biasv[4];
#pragma unroll
  for (int nt = 0; nt < 4; ++nt) biasv[nt] = bih[nt * 16 + m] + bhh[nt * 16 + m];
  const float woutl = Wout[lane];
  const float bout0 = bout[0];

  // zero own wave's h state (h_{-1} = 0): 72 dwords
  {
    unsigned int* hz = reinterpret_cast<unsigned int*>(&hbl[w][0][0]);
    hz[lane] = 0u;
    if (lane < 8) hz[64 + lane] = 0u;
  }
  __syncthreads();   // wihL ready; ONLY barrier in the kernel

  float hv0 = 0.f, hv1 = 0.f;

  for (int c = 0; c < NCH; ++c) {
    // ---- STAGE: cvt pld(c) -> bf16, ds_write into per-wave stage (linear->[r][t][d])
#pragma unroll
    for (int i = 0; i < 7; ++i) {
      if (i < 6 || lane < 16) {
        const int fi  = i * 256 + lane * 4;      // float index within 1600-float row chunk
        const int tl_ = fi / 200;
        const int c2  = fi - tl_ * 200;          // multiple of 4
#pragma unroll
        for (int r = 0; r < 2; ++r) {
          f32x4 p = pld[r][i];
          u32x2 d2;
          d2[0] = (unsigned)f2bf(p[0]) | ((unsigned)f2bf(p[1]) << 16);
          d2[1] = (unsigned)f2bf(p[2]) | ((unsigned)f2bf(p[3]) << 16);
          *reinterpret_cast<u32x2*>(&stg[w][r][tl_ * STG_T + c2]) = d2;
        }
      }
    }
    // ---- issue next chunk's loads now (regs free; in flight through proj+steps)
    if (c + 1 < NCH) LOADC(c + 1);

    // ---- PROJ: A[row = rb*8+t'][k=d] from stage; B from wihL; full 16-row tile
    f32x4 acc[4];
#pragma unroll
    for (int nt = 0; nt < 4; ++nt) acc[nt] = (f32x4)(biasv[nt]);
    {
      const unsigned short* sp = &stg[w][m >> 3][(m & 7) * STG_T];
#pragma unroll
      for (int ks = 0; ks < 7; ++ks) {
        bf16x8 av = *reinterpret_cast<const bf16x8*>(sp + (ks < 6 ? ks * 32 + g * 8 : 192));
        if (ks == 6 && g != 0) av = (bf16x8)0;   // k >= 200 tail
#pragma unroll
        for (int nt = 0; nt < 4; ++nt) {
          bf16x8 bv = *reinterpret_cast<const bf16x8*>(&wihL[nt * 7 + ks][lane][0]);
          acc[nt] = __builtin_amdgcn_mfma_f32_16x16x32_bf16(av, bv, acc[nt], 0, 0, 0);
        }
      }
    }
    // D row = g*4+rr -> batch rb = g>>1, t' = (g&1)*4+rr; write xp[t'][h][rb]
#pragma unroll
    for (int nt = 0; nt < 4; ++nt)
#pragma unroll
      for (int rr = 0; rr < 4; ++rr)
        xpl[w][(g & 1) * 4 + rr][nt * 16 + m][g >> 1] = acc[nt][rr];

    // ---- 8 recurrence steps, fully in-wave (LDS ops in-order per wave)
#pragma unroll
    for (int tl = 0; tl < CT; ++tl) {
      f32x4 racc[4];
#pragma unroll
      for (int nt = 0; nt < 4; ++nt) {   // C rows r: batch = r&1 -> {b0,b1,b0,b1}
        f32x2 q = *reinterpret_cast<const f32x2*>(&xpl[w][tl][nt * 16 + m][0]);
        racc[nt][0] = q[0]; racc[nt][1] = q[1]; racc[nt][2] = q[0]; racc[nt][3] = q[1];
      }
      // A[r][k] = h_{r&1}[k]: lane (m,g) reads hbl[m&1] at k = g*8 (+32)
      bf16x8 ha0 = *reinterpret_cast<const bf16x8*>(&hbl[w][m & 1][g * 8]);
      bf16x8 ha1 = *reinterpret_cast<const bf16x8*>(&hbl[w][m & 1][32 + g * 8]);
#pragma unroll
      for (int nt = 0; nt < 4; ++nt)
        racc[nt] = __builtin_amdgcn_mfma_f32_16x16x32_bf16(ha0, whhf[nt][0], racc[nt], 0, 0, 0);
#pragma unroll
      for (int nt = 0; nt < 4; ++nt)
        racc[nt] = __builtin_amdgcn_mfma_f32_16x16x32_bf16(ha1, whhf[nt][1], racc[nt], 0, 0, 0);
      // each g-group owns n-tile nt=g; rr=0 -> batch0, rr=1 -> batch1; col = g*16+m = lane
      float v0 = (g == 0) ? racc[0][0] : (g == 1) ? racc[1][0] : (g == 2) ? racc[2][0] : racc[3][0];
      float v1 = (g == 0) ? racc[0][1] : (g == 1) ? racc[1][1] : (g == 2) ? racc[2][1] : racc[3][1];
      v0 = tanh_fast(v0); v1 = tanh_fast(v1);
      hv0 = v0; hv1 = v1;
      hbl[w][0][lane] = f2bf(v0);
      hbl[w][1][lane] = f2bf(v1);
    }
  }

  // ---- epilogue: out[r0+b] = sigmoid(h_last[b] . Wout + bout), reduce over 64 lanes
  float s0 = hv0 * woutl, s1 = hv1 * woutl;
#pragma unroll
  for (int mask = 1; mask < 64; mask <<= 1) {
    s0 += __shfl_xor(s0, mask, 64);
    s1 += __shfl_xor(s1, mask, 64);
  }
  if (lane == 0) {
    out[r0]     = __builtin_amdgcn_rcpf(1.f + exp2f(-(s0 + bout0) * 1.4426950408889634f));
    out[r0 + 1] = __builtin_amdgcn_rcpf(1.f + exp2f(-(s1 + bout0) * 1.4426950408889634f));
  }
}

extern "C" void kernel_launch(void* const* d_in, const int* in_sizes, int n_in,
                              void* d_out, int out_size, void* d_ws, size_t ws_size,
                              hipStream_t stream) {
  const float* x    = (const float*)d_in[0];
  const float* Wih  = (const float*)d_in[1];
  const float* Whh  = (const float*)d_in[2];
  const float* bih  = (const float*)d_in[3];
  const float* bhh  = (const float*)d_in[4];
  const float* Wout = (const float*)d_in[5];
  const float* bout = (const float*)d_in[6];
  float* out = (float*)d_out;

  const int B = in_sizes[0] / (TSEQ * DIN);   // 4096
  rnn_fused<<<dim3(B / 8), dim3(256), 0, stream>>>(x, Wih, Whh, bih, bhh, Wout, bout, out);
}

// Round 5
// 98.397 us; speedup vs baseline: 1.1363x; 1.0900x over previous
//
#include <hip/hip_runtime.h>
#include <hip/hip_bf16.h>

// RNN_73048803770905: fused [B,T,200]x[200,64] projection + 128-step tanh RNN + sigmoid head.
// B=4096, T=128, D_IN=200, H=64. 419 MB x read once; floor ~67us @6.3TB/s.
// R5: R1-R4 all equilibrated at 4.1-4.4 TB/s with duty-cycled loads (issue batch ->
// drain to zero -> reissue). Fix: global_load_lds f32 staging, double-buffered, with
// COUNTED vmcnt waits (steady vmcnt(8), never 0) so loads stay in flight continuously
// across raw s_barriers. Block = 8 rows, 512 blocks, 2 blocks/CU, 63KB static LDS.
// Cooperative R1-style proj (wave w owns t=4c+w) + recurrence (wave w owns h-cols w*16..).

#define TSEQ 128
#define DIN  200
#define HID  64
#define NB   8
#define TC   4
#define NCH  (TSEQ/TC)
#define RSTRIDE 804   // floats per stage row: 4*200 + 4 pad (16B-aligned, bank-spread)

typedef short bf16x8 __attribute__((ext_vector_type(8)));
typedef float f32x4  __attribute__((ext_vector_type(4)));
typedef const __attribute__((address_space(1))) unsigned int GU32;
typedef __attribute__((address_space(3))) unsigned int LU32;

__device__ __forceinline__ unsigned short f2bf(float f) {
  __hip_bfloat16 h = __float2bfloat16(f);
  return __builtin_bit_cast(unsigned short, h);
}
__device__ __forceinline__ bf16x8 cvt8(f32x4 a, f32x4 b) {
  bf16x8 r;
#pragma unroll
  for (int i = 0; i < 4; ++i) { r[i] = (short)f2bf(a[i]); r[4 + i] = (short)f2bf(b[i]); }
  return r;
}
// tanh(x) = 1 - 2/(1 + 2^(x*2/ln2)); v_exp_f32 handles the extremes.
__device__ __forceinline__ float tanh_fast(float x) {
  float e = exp2f(x * 2.885390081777927f);
  float r = __builtin_amdgcn_rcpf(1.f + e);
  return __builtin_fmaf(-2.f, r, 1.f);
}
// LDS-only barrier: does NOT drain vmcnt -> staged loads stay in flight.
__device__ __forceinline__ void barrier_lds() {
  asm volatile("s_waitcnt lgkmcnt(0)" ::: "memory");
  __builtin_amdgcn_s_barrier();
  __builtin_amdgcn_sched_barrier(0);
}
__device__ __forceinline__ void wait_vm8() {
  asm volatile("s_waitcnt vmcnt(8)" ::: "memory");
  __builtin_amdgcn_sched_barrier(0);
}
__device__ __forceinline__ void wait_vm0() {
  asm volatile("s_waitcnt vmcnt(0)" ::: "memory");
  __builtin_amdgcn_sched_barrier(0);
}

__global__ __launch_bounds__(256, 2) void rnn_fused(
    const float* __restrict__ x,   const float* __restrict__ Wih,
    const float* __restrict__ Whh, const float* __restrict__ bih,
    const float* __restrict__ bhh, const float* __restrict__ Wout,
    const float* __restrict__ bout, float* __restrict__ out)
{
  __shared__ float          stg[2][NB][RSTRIDE];   // x f32 stage, dbuf: 51456 B
  __shared__ float          xp[TC][NB][68];        // xp chunk f32 (+ final h): 8704 B
  __shared__ unsigned short hbuf[2][16][72];       // h dbuf bf16 bits: 4608 B  (63.3 KB total)

  const int tid  = threadIdx.x;
  const int w    = tid >> 6;
  const int lane = tid & 63;
  const int m    = lane & 15;
  const int g    = lane >> 4;
  const int b0   = blockIdx.x * NB;

  // ---- weights into registers (all global loads BEFORE the staged-load stream) ----
  bf16x8 wihf[4][7];   // B[k=d][n=h]: lane h = nt*16+m, d = ks*32+g*8+j
#pragma unroll
  for (int nt = 0; nt < 4; ++nt) {
    const float* wr = Wih + (size_t)(nt * 16 + m) * DIN;
#pragma unroll
    for (int ks = 0; ks < 7; ++ks) {
      const int d = ks * 32 + g * 8;
      if (d + 8 <= DIN)
        wihf[nt][ks] = cvt8(*reinterpret_cast<const f32x4*>(wr + d),
                            *reinterpret_cast<const f32x4*>(wr + d + 4));
      else
        wihf[nt][ks] = (bf16x8)0;
    }
  }
  bf16x8 whhf[2];      // B[k][n=h]: wave owns n-tile w (h = w*16+m), k = hf*32+g*8+j
#pragma unroll
  for (int hf = 0; hf < 2; ++hf) {
    const float* wr = Whh + (size_t)(w * 16 + m) * HID + hf * 32 + g * 8;
    whhf[hf] = cvt8(*reinterpret_cast<const f32x4*>(wr),
                    *reinterpret_cast<const f32x4*>(wr + 4));
  }
  float biasv[4];
#pragma unroll
  for (int nt = 0; nt < 4; ++nt) biasv[nt] = bih[nt * 16 + m] + bhh[nt * 16 + m];

  // ensure no weight load is still outstanding (keeps vmcnt arithmetic exact)
  wait_vm0();

  // ---- staged loads: wave w owns rows {2w, 2w+1}; 8 global_load_lds per chunk ----
  auto LOADC = [&](int buf, int c) {
#pragma unroll
    for (int r = 0; r < 2; ++r) {
      const int row = w * 2 + r;
      const float* gb = x + (size_t)(b0 + row) * (TSEQ * DIN) + (size_t)c * (TC * DIN);
      float* lb = &stg[buf][row][0];
#pragma unroll
      for (int i = 0; i < 3; ++i)
        __builtin_amdgcn_global_load_lds((GU32*)(gb + i * 256 + lane * 4),
                                         (LU32*)(lb + i * 256), 16, 0, 0);
      if (lane < 8)
        __builtin_amdgcn_global_load_lds((GU32*)(gb + 768 + lane * 4),
                                         (LU32*)(lb + 768), 16, 0, 0);
    }
  };
  LOADC(0, 0);
  LOADC(1, 1);

  // zero h state (h_{-1} = 0)
  for (int i = tid; i < 2 * 16 * 72 / 2; i += 256)
    reinterpret_cast<unsigned int*>(&hbuf[0][0][0])[i] = 0u;

  for (int c = 0; c < NCH; ++c) {
    const int buf = c & 1;
    // (1) chunk c landed for THIS wave (8 newest = chunk c+1 stay in flight), then all waves
    if (c + 1 < NCH) wait_vm8(); else wait_vm0();
    __builtin_amdgcn_s_barrier();
    __builtin_amdgcn_sched_barrier(0);

    // (2) A-frags from stage: row m (rows 8-15 garbage, row-local, discarded), t = w
    bf16x8 afr[7];
    {
      const float* sp = &stg[buf][0][0];
#pragma unroll
      for (int ks = 0; ks < 7; ++ks) {
        const int off = m * RSTRIDE + w * 200 + (ks < 6 ? ks * 32 + g * 8 : 192);
        afr[ks] = cvt8(*reinterpret_cast<const f32x4*>(sp + off),
                       *reinterpret_cast<const f32x4*>(sp + off + 4));
      }
      if (g != 0) afr[6] = (bf16x8)0;   // k >= 200 tail
    }
    barrier_lds();   // all waves done reading stg[buf]

    // (3) refill stg[buf] with chunk c+2 (in flight through proj + 4 steps)
    if (c + 2 < NCH) LOADC(buf, c + 2);

    // (4) proj: xp(t=4c+w) = x_t * Wih^T + bias
    f32x4 acc[4];
#pragma unroll
    for (int nt = 0; nt < 4; ++nt) acc[nt] = (f32x4)(biasv[nt]);
#pragma unroll
    for (int ks = 0; ks < 7; ++ks)
#pragma unroll
      for (int nt = 0; nt < 4; ++nt)
        acc[nt] = __builtin_amdgcn_mfma_f32_16x16x32_bf16(afr[ks], wihf[nt][ks], acc[nt], 0, 0, 0);
    // D: col = lane&15, row = g*4+rr (valid rows 0-7 <=> g<2)
    if (g < 2) {
#pragma unroll
      for (int nt = 0; nt < 4; ++nt)
#pragma unroll
        for (int rr = 0; rr < 4; ++rr)
          xp[w][g * 4 + rr][nt * 16 + m] = acc[nt][rr];
    }
    barrier_lds();

    // (5) recurrence: 4 steps; wave owns h cols w*16..w*16+15
#pragma unroll
    for (int tl = 0; tl < TC; ++tl) {
      const int tt = c * TC + tl;
      const int rb = tt & 1, pb = rb ^ 1;
      bf16x8 ha0 = *reinterpret_cast<const bf16x8*>(&hbuf[pb][m][g * 8]);
      bf16x8 ha1 = *reinterpret_cast<const bf16x8*>(&hbuf[pb][m][32 + g * 8]);
      f32x4 racc;
#pragma unroll
      for (int r = 0; r < 4; ++r) racc[r] = xp[tl][g * 4 + r][w * 16 + m];
      racc = __builtin_amdgcn_mfma_f32_16x16x32_bf16(ha0, whhf[0], racc, 0, 0, 0);
      racc = __builtin_amdgcn_mfma_f32_16x16x32_bf16(ha1, whhf[1], racc, 0, 0, 0);
      if (g < 2) {
#pragma unroll
        for (int r = 0; r < 4; ++r) {
          const float hv = tanh_fast(racc[r]);
          hbuf[rb][g * 4 + r][w * 16 + m] = f2bf(hv);
          if (tt == TSEQ - 1) xp[0][g * 4 + r][w * 16 + m] = hv;   // final h, f32
        }
      }
      barrier_lds();
    }
  }

  // ---- epilogue: out[b] = sigmoid(h_last . Wout + bout) ----
  if (tid < 64) {
    const int b  = lane >> 3;        // 0..7
    const int j0 = (lane & 7) * 8;   // 0..56
    float s = 0.f;
#pragma unroll
    for (int j = 0; j < 8; ++j) s += xp[0][b][j0 + j] * Wout[j0 + j];
    s += __shfl_xor(s, 1, 64);
    s += __shfl_xor(s, 2, 64);
    s += __shfl_xor(s, 4, 64);
    if ((lane & 7) == 0) {
      const float z = s + bout[0];
      out[b0 + b] = __builtin_amdgcn_rcpf(1.f + exp2f(-z * 1.4426950408889634f));
    }
  }
}

extern "C" void kernel_launch(void* const* d_in, const int* in_sizes, int n_in,
                              void* d_out, int out_size, void* d_ws, size_t ws_size,
                              hipStream_t stream) {
  const float* x    = (const float*)d_in[0];
  const float* Wih  = (const float*)d_in[1];
  const float* Whh  = (const float*)d_in[2];
  const float* bih  = (const float*)d_in[3];
  const float* bhh  = (const float*)d_in[4];
  const float* Wout = (const float*)d_in[5];
  const float* bout = (const float*)d_in[6];
  float* out = (float*)d_out;

  const int B = in_sizes[0] / (TSEQ * DIN);   // 4096
  rnn_fused<<<dim3(B / NB), dim3(256), 0, stream>>>(x, Wih, Whh, bih, bhh, Wout, bout, out);
}